// Round 10
// baseline (369.891 us; speedup 1.0000x reference)
//
#include <hip/hip_runtime.h>
#include <hip/hip_bf16.h>

#define NN 100000
#define EE 500000
#define DD 128
#define NDEPTH 2
#define EPSV 1e-5f
#define NCHUNK 1024
#define NBLK ((NN + NCHUNK - 1) / NCHUNK)   // 98
#define NAB 6250     // aggbn blocks (16 waves x 1 node = 16 nodes/block)

typedef __attribute__((ext_vector_type(4))) float f32x4;
typedef __attribute__((ext_vector_type(4))) int i32x4;
typedef __attribute__((ext_vector_type(2))) unsigned int u32x2;
typedef __attribute__((ext_vector_type(8))) short bf16x8;
typedef __attribute__((ext_vector_type(4))) short bf16x4;

static __device__ __forceinline__ short f2bf(float x) {
  union { float f; unsigned u; } v; v.f = x;
  unsigned r = v.u + 0x7fffu + ((v.u >> 16) & 1u);  // round-to-nearest-even
  return (short)(r >> 16);
}
static __device__ __forceinline__ float bfbits2f(unsigned hi16) {
  union { unsigned u; float f; } v; v.u = hi16;
  return v.f;
}

// ---- convert both weight tensors to bf16 once ----
__global__ void k_convert_w(const float* __restrict__ lw, const float* __restrict__ gw,
                            short* __restrict__ wbf) {
  int i = blockIdx.x * 256 + threadIdx.x;
  if (i < NDEPTH * DD * DD) {
    wbf[i] = f2bf(lw[i]);
    wbf[NDEPTH * DD * DD + i] = f2bf(gw[i]);
  }
}

// ---- edge pass 1: degree (weighted) + count histogram by col ----
__global__ void k_edge1(const int* __restrict__ ei, const float* __restrict__ ew,
                        float* __restrict__ deg, int* __restrict__ cnt) {
  int e = blockIdx.x * 256 + threadIdx.x;
  if (e < EE) {
    int c = ei[EE + e];
    atomicAdd(deg + c, ew[e]);
    atomicAdd(cnt + c, 1);
  }
}

__global__ void k_dinv(const float* __restrict__ deg, float* __restrict__ dinv) {
  int i = blockIdx.x * 256 + threadIdx.x;
  if (i < NN) {
    float d = deg[i];
    dinv[i] = d > 0.f ? rsqrtf(d) : 0.f;
  }
}

// ---- scan stage 1 ----
__global__ __launch_bounds__(256) void k_scan_part(const int* __restrict__ cnt,
                                                   int* __restrict__ part) {
  int b = blockIdx.x, t = threadIdx.x, lane = t & 63, wid = t >> 6;
  int base = b * NCHUNK + t * 4;
  int s = 0;
  if (base + 3 < NN) {
    i32x4 v = *(const i32x4*)(cnt + base);
    s = v[0] + v[1] + v[2] + v[3];
  } else {
    for (int j = 0; j < 4; ++j) if (base + j < NN) s += cnt[base + j];
  }
  for (int d = 32; d > 0; d >>= 1) s += __shfl_down(s, d);
  __shared__ int wsum[4];
  if (lane == 0) wsum[wid] = s;
  __syncthreads();
  if (t == 0) part[b] = wsum[0] + wsum[1] + wsum[2] + wsum[3];
}

// ---- scan stage 2 ----
__global__ void k_scan_mid(int* __restrict__ part, int* __restrict__ rowptr) {
  __shared__ int sm[128];
  int t = threadIdx.x;
  int v = (t < NBLK) ? part[t] : 0;
  sm[t] = v;
  __syncthreads();
  for (int off = 1; off < 128; off <<= 1) {
    int a = sm[t];
    int b = (t >= off) ? sm[t - off] : 0;
    __syncthreads();
    sm[t] = a + b;
    __syncthreads();
  }
  if (t < NBLK) part[t] = (t == 0) ? 0 : sm[t - 1];
  if (t == 127) rowptr[NN] = sm[127];
}

// ---- scan stage 3 ----
__global__ __launch_bounds__(256) void k_scan_final(const int* __restrict__ cnt,
    const int* __restrict__ part, int* __restrict__ rowptr, int* __restrict__ cursor) {
  int b = blockIdx.x, t = threadIdx.x, lane = t & 63, wid = t >> 6;
  int base = b * NCHUNK + t * 4;
  int c0 = 0, c1 = 0, c2 = 0, c3 = 0;
  if (base + 3 < NN) {
    i32x4 v = *(const i32x4*)(cnt + base);
    c0 = v[0]; c1 = v[1]; c2 = v[2]; c3 = v[3];
  } else {
    if (base < NN) c0 = cnt[base];
    if (base + 1 < NN) c1 = cnt[base + 1];
    if (base + 2 < NN) c2 = cnt[base + 2];
    if (base + 3 < NN) c3 = cnt[base + 3];
  }
  int s = c0 + c1 + c2 + c3;
  int v = s;
  for (int d = 1; d < 64; d <<= 1) {
    int u = __shfl_up(v, d);
    if (lane >= d) v += u;
  }
  __shared__ int wsum[4];
  if (lane == 63) wsum[wid] = v;
  __syncthreads();
  int woff = 0;
  for (int w = 0; w < wid; ++w) woff += wsum[w];
  int excl = part[b] + woff + (v - s);
  if (base < NN)     { rowptr[base]     = excl; cursor[base]     = excl; excl += c0; }
  if (base + 1 < NN) { rowptr[base + 1] = excl; cursor[base + 1] = excl; excl += c1; }
  if (base + 2 < NN) { rowptr[base + 2] = excl; cursor[base + 2] = excl; excl += c2; }
  if (base + 3 < NN) { rowptr[base + 3] = excl; cursor[base + 3] = excl; }
}

// ---- edge pass 2: bucket (row, norm) by col ----
__global__ void k_edge2(const int* __restrict__ ei, const float* __restrict__ ew,
                        const float* __restrict__ dinv, int* __restrict__ cursor,
                        int* __restrict__ srow, float* __restrict__ snorm) {
  int e = blockIdx.x * 256 + threadIdx.x;
  if (e < EE) {
    int r = ei[e], c = ei[EE + e];
    float nrm = dinv[r] * ew[e] * dinv[c];
    int pos = atomicAdd(cursor + c, 1);
    srow[pos] = r;
    snorm[pos] = nrm;
  }
}

// ---- dual GEMM, LDS-staged weights. 512 threads = 8 waves x 16 rows.
// hl -> tmpb (bf16), hgemm -> hg (bf16). APPLY=1: input is bf16 pre-BN h,
// apply per-column scale/bias + ReLU before use. In-place tmpb is row-safe
// (each row fully loaded to registers before any store).
template<int APPLY>
__global__ __launch_bounds__(512) void k_dualgemm(const void* __restrict__ Hv,
    const short* __restrict__ Wl, const short* __restrict__ Wg,
    const float* __restrict__ sb, unsigned short* __restrict__ tmpo,
    unsigned short* __restrict__ hg) {
  __shared__ short lw[2 * DD * DD];   // 64 KB
  int tid = threadIdx.x;

  // stage: 4096 16B-units; swizzled global source -> linear LDS
#pragma unroll
  for (int c = 0; c < 8; ++c) {
    int q = c * 512 + tid;
    int region = q >> 11;            // 0 = Wl, 1 = Wg
    int row = (q >> 4) & 127;
    int u = q & 15;
    const short* src = (region ? Wg : Wl) + row * DD + ((u ^ (row & 7)) * 8);
    *(bf16x8*)(lw + q * 8) = *(const bf16x8*)src;
  }

  int lane = tid & 63, wv = tid >> 6;
  int row0 = blockIdx.x * 128 + wv * 16;
  int m = lane & 15, g = lane >> 4;

  bf16x8 hb[4];
  if (row0 < NN) {
#pragma unroll
    for (int s = 0; s < 4; ++s) {
      float f[8];
      if (APPLY) {
        const unsigned short* H = (const unsigned short*)Hv;
        bf16x8 hv = *(const bf16x8*)(H + (size_t)(row0 + m) * DD + s * 32 + g * 8);
#pragma unroll
        for (int k2 = 0; k2 < 8; ++k2)
          f[k2] = bfbits2f(((unsigned)(unsigned short)hv[k2]) << 16);
      } else {
        const float* H = (const float*)Hv;
        f32x4 v0 = *(const f32x4*)(H + (size_t)(row0 + m) * DD + s * 32 + g * 8);
        f32x4 v1 = *(const f32x4*)(H + (size_t)(row0 + m) * DD + s * 32 + g * 8 + 4);
#pragma unroll
        for (int k2 = 0; k2 < 4; ++k2) { f[k2] = v0[k2]; f[k2 + 4] = v1[k2]; }
      }
      if (APPLY) {
        f32x4 sc0 = *(const f32x4*)(sb + s * 32 + g * 8);
        f32x4 sc1 = *(const f32x4*)(sb + s * 32 + g * 8 + 4);
        f32x4 bi0 = *(const f32x4*)(sb + DD + s * 32 + g * 8);
        f32x4 bi1 = *(const f32x4*)(sb + DD + s * 32 + g * 8 + 4);
#pragma unroll
        for (int k2 = 0; k2 < 4; ++k2) {
          f[k2]     = fmaxf(f[k2]     * sc0[k2] + bi0[k2], 0.f);
          f[k2 + 4] = fmaxf(f[k2 + 4] * sc1[k2] + bi1[k2], 0.f);
        }
      }
      bf16x8 tt;
#pragma unroll
      for (int k2 = 0; k2 < 8; ++k2) tt[k2] = f2bf(f[k2]);
      hb[s] = tt;
    }
  }

  __syncthreads();
  if (row0 >= NN) return;

  int mx = m & 7;
#pragma unroll
  for (int t = 0; t < 8; ++t) {
    f32x4 accl; accl[0] = 0.f; accl[1] = 0.f; accl[2] = 0.f; accl[3] = 0.f;
    f32x4 accg = accl;
#pragma unroll
    for (int s = 0; s < 4; ++s) {
      int u = (s * 4 + g) ^ mx;
      int base = (t * 16 + m) * DD + u * 8;
      bf16x8 wlf = *(const bf16x8*)(lw + base);
      bf16x8 wgf = *(const bf16x8*)(lw + DD * DD + base);
      accl = __builtin_amdgcn_mfma_f32_16x16x32_bf16(wlf, hb[s], accl, 0, 0, 0);
      accg = __builtin_amdgcn_mfma_f32_16x16x32_bf16(wgf, hb[s], accg, 0, 0, 0);
    }
    size_t r = (size_t)(row0 + m);
    bf16x4 l4, h4;
    l4[0] = f2bf(accl[0]); l4[1] = f2bf(accl[1]); l4[2] = f2bf(accl[2]); l4[3] = f2bf(accl[3]);
    h4[0] = f2bf(accg[0]); h4[1] = f2bf(accg[1]); h4[2] = f2bf(accg[2]); h4[3] = f2bf(accg[3]);
    *(bf16x4*)(tmpo + r * DD + t * 16 + g * 4) = l4;
    *(bf16x4*)(hg + r * DD + t * 16 + g * 4) = h4;
  }
}

// ---- fused aggregation + BN stats: 1024 threads = 16 waves x 1 node.
// tmpb[node] (bf16) += sum norm * hg[srcrow]; per-block column sum/sumsq partials
// computed on the ROUNDED stored values (consistent with downstream consumers).
__global__ __launch_bounds__(1024) void k_aggbn(const int* __restrict__ rowptr,
    const int* __restrict__ srow, const float* __restrict__ snorm,
    const unsigned int* __restrict__ hgu, unsigned int* __restrict__ tmpu,
    float* __restrict__ psum, float* __restrict__ pss) {
  int tid = threadIdx.x, lane = tid & 63, wv = tid >> 6;   // 16 waves
  int b = blockIdx.x;
  int node = b * 16 + wv;                                   // NAB*16 == NN
  int beg = rowptr[node], end = rowptr[node + 1];
  float ax = 0.f, ay = 0.f;
  for (int j = beg; j < end; ++j) {
    int r = srow[j];
    float w = snorm[j];
    unsigned u = hgu[r * 64 + lane];      // 2 bf16: cols 2*lane, 2*lane+1
    ax += w * bfbits2f(u << 16);
    ay += w * bfbits2f(u & 0xffff0000u);
  }
  unsigned* tp = tmpu + (size_t)node * 64 + lane;
  unsigned hl = *tp;
  float t0 = bfbits2f(hl << 16) + ax;
  float t1 = bfbits2f(hl & 0xffff0000u) + ay;
  unsigned p0 = (unsigned)(unsigned short)f2bf(t0);
  unsigned p1 = (unsigned)(unsigned short)f2bf(t1);
  *tp = p0 | (p1 << 16);
  float r0 = bfbits2f(p0 << 16), r1 = bfbits2f(p1 << 16);

  __shared__ float red[16][256];
  f32x4 pk; pk[0] = r0; pk[1] = r1; pk[2] = r0 * r0; pk[3] = r1 * r1;
  *(f32x4*)&red[wv][lane * 4] = pk;
  __syncthreads();
  if (tid < 256) {
    float v = 0.f;
#pragma unroll
    for (int w = 0; w < 16; ++w) v += red[w][tid];
    int col = (tid >> 2) * 2 + (tid & 1);
    if (((tid >> 1) & 1) == 0) psum[(size_t)b * DD + col] = v;
    else                       pss [(size_t)b * DD + col] = v;
  }
}

// ---- reduce partials -> per-column scale/bias (folds gamma/beta/rsqrt) ----
__global__ __launch_bounds__(256) void k_bnreduce(const float* __restrict__ psum,
    const float* __restrict__ pss, const float* __restrict__ gamma,
    const float* __restrict__ beta, float* __restrict__ sb) {
  int col = blockIdx.x, t = threadIdx.x;
  float s = 0.f, q = 0.f;
  for (int i = t; i < NAB; i += 256) {
    s += psum[(size_t)i * DD + col];
    q += pss[(size_t)i * DD + col];
  }
  for (int d = 32; d > 0; d >>= 1) { s += __shfl_down(s, d); q += __shfl_down(q, d); }
  __shared__ float lws[4], lwq[4];
  int wid = t >> 6, lane = t & 63;
  if (lane == 0) { lws[wid] = s; lwq[wid] = q; }
  __syncthreads();
  if (t == 0) {
    float S = lws[0] + lws[1] + lws[2] + lws[3];
    float Q = lwq[0] + lwq[1] + lwq[2] + lwq[3];
    float mean = S * (1.f / NN);
    float var = Q * (1.f / NN) - mean * mean;
    float sc = rsqrtf(var + EPSV) * gamma[col];
    sb[col] = sc;
    sb[DD + col] = beta[col] - mean * sc;
  }
}

// ---- final BN apply: bf16 h -> f32 out, x*scale + bias (no relu) ----
__global__ void k_bnapply(const unsigned int* __restrict__ hb, const float* __restrict__ sb,
                          float* __restrict__ out) {
  int i = blockIdx.x * 256 + threadIdx.x;   // over NN*DD/4
  if (i >= NN * DD / 4) return;
  int d0 = (i * 4) & (DD - 1);
  u32x2 u = *(const u32x2*)(hb + i * 2);
  f32x4 o;
  o[0] = bfbits2f(u[0] << 16)          * sb[d0]     + sb[DD + d0];
  o[1] = bfbits2f(u[0] & 0xffff0000u)  * sb[d0 + 1] + sb[DD + d0 + 1];
  o[2] = bfbits2f(u[1] << 16)          * sb[d0 + 2] + sb[DD + d0 + 2];
  o[3] = bfbits2f(u[1] & 0xffff0000u)  * sb[d0 + 3] + sb[DD + d0 + 3];
  ((f32x4*)out)[i] = o;
}

extern "C" void kernel_launch(void* const* d_in, const int* in_sizes, int n_in,
                              void* d_out, int out_size, void* d_ws, size_t ws_size,
                              hipStream_t stream) {
  const float* x     = (const float*)d_in[0];
  const int*   ei    = (const int*)d_in[1];
  const float* ew    = (const float*)d_in[2];
  const float* lin_w = (const float*)d_in[3];
  const float* gcn_w = (const float*)d_in[4];
  const float* gamma = (const float*)d_in[5];
  const float* beta  = (const float*)d_in[6];
  float* out = (float*)d_out;

  char* ws = (char*)d_ws;
  size_t off = 0;
  auto alloc = [&](size_t bytes) -> void* {
    void* p = ws + off;
    off += (bytes + 255) & ~(size_t)255;
    return p;
  };
  unsigned short* hg   = (unsigned short*)alloc((size_t)NN * DD * 2);  // bf16
  unsigned short* tmpb = (unsigned short*)alloc((size_t)NN * DD * 2);  // bf16 h
  float* snorm  = (float*)alloc((size_t)EE * 4);
  int*   srow   = (int*)alloc((size_t)EE * 4);
  float* deg    = (float*)alloc((size_t)NN * 4);
  float* dinv   = (float*)alloc((size_t)NN * 4);
  int*   rowptr = (int*)alloc((size_t)(NN + 1) * 4);
  int*   cursor = (int*)alloc((size_t)NN * 4);
  int*   cnt    = (int*)alloc((size_t)NN * 4);
  int*   part   = (int*)alloc((size_t)NBLK * 4);
  short* wbf    = (short*)alloc((size_t)2 * NDEPTH * DD * DD * 2);
  float* psum   = (float*)alloc((size_t)NAB * DD * 4);
  float* pss    = (float*)alloc((size_t)NAB * DD * 4);
  float* sb     = (float*)alloc((size_t)2 * DD * 4);

  hipMemsetAsync(deg, 0, (size_t)NN * 4, stream);
  hipMemsetAsync(cnt, 0, (size_t)NN * 4, stream);

  k_convert_w<<<(NDEPTH * DD * DD + 255) / 256, 256, 0, stream>>>(lin_w, gcn_w, wbf);
  k_edge1<<<(EE + 255) / 256, 256, 0, stream>>>(ei, ew, deg, cnt);
  k_dinv<<<(NN + 255) / 256, 256, 0, stream>>>(deg, dinv);
  k_scan_part<<<NBLK, 256, 0, stream>>>(cnt, part);
  k_scan_mid<<<1, 128, 0, stream>>>(part, rowptr);
  k_scan_final<<<NBLK, 256, 0, stream>>>(cnt, part, rowptr, cursor);
  k_edge2<<<(EE + 255) / 256, 256, 0, stream>>>(ei, ew, dinv, cursor, srow, snorm);

  const short* Wl0 = wbf;
  const short* Wg0 = wbf + (size_t)NDEPTH * DD * DD;
  const short* Wl1 = wbf + (size_t)DD * DD;
  const short* Wg1 = wbf + (size_t)NDEPTH * DD * DD + (size_t)DD * DD;
  const int GEMMBLK = (NN + 127) / 128;   // 782

  // layer 0
  k_dualgemm<0><<<GEMMBLK, 512, 0, stream>>>(x, Wl0, Wg0, sb, tmpb, hg);
  k_aggbn<<<NAB, 1024, 0, stream>>>(rowptr, srow, snorm, (const unsigned int*)hg,
                                    (unsigned int*)tmpb, psum, pss);
  k_bnreduce<<<DD, 256, 0, stream>>>(psum, pss, gamma, beta, sb);

  // layer 1 (BN+ReLU folded into H load; in-place tmpb is row-safe)
  k_dualgemm<1><<<GEMMBLK, 512, 0, stream>>>(tmpb, Wl1, Wg1, sb, tmpb, hg);
  k_aggbn<<<NAB, 1024, 0, stream>>>(rowptr, srow, snorm, (const unsigned int*)hg,
                                    (unsigned int*)tmpb, psum, pss);
  k_bnreduce<<<DD, 256, 0, stream>>>(psum, pss, gamma + DD, beta + DD, sb);
  k_bnapply<<<(NN * DD / 4 + 255) / 256, 256, 0, stream>>>((const unsigned int*)tmpb, sb, out);
}

// Round 11
// 285.218 us; speedup vs baseline: 1.2969x; 1.2969x over previous
//
#include <hip/hip_runtime.h>
#include <hip/hip_bf16.h>

#define NN 100000
#define EE 500000
#define DD 128
#define NDEPTH 2
#define EPSV 1e-5f
#define NCHUNK 1024
#define NBLK ((NN + NCHUNK - 1) / NCHUNK)   // 98
#define NPB 2000     // bnstats blocks
#define RPB 50       // rows per bnstats block

typedef __attribute__((ext_vector_type(4))) float f32x4;
typedef __attribute__((ext_vector_type(4))) int i32x4;
typedef __attribute__((ext_vector_type(2))) unsigned int u32x2;
typedef __attribute__((ext_vector_type(8))) short bf16x8;
typedef __attribute__((ext_vector_type(4))) short bf16x4;

static __device__ __forceinline__ short f2bf(float x) {
  union { float f; unsigned u; } v; v.f = x;
  unsigned r = v.u + 0x7fffu + ((v.u >> 16) & 1u);  // round-to-nearest-even
  return (short)(r >> 16);
}
static __device__ __forceinline__ float bfbits2f(unsigned hi16) {
  union { unsigned u; float f; } v; v.u = hi16;
  return v.f;
}

// ---- convert both weight tensors to bf16 once ----
__global__ void k_convert_w(const float* __restrict__ lw, const float* __restrict__ gw,
                            short* __restrict__ wbf) {
  int i = blockIdx.x * 256 + threadIdx.x;
  if (i < NDEPTH * DD * DD) {
    wbf[i] = f2bf(lw[i]);
    wbf[NDEPTH * DD * DD + i] = f2bf(gw[i]);
  }
}

// ---- edge pass 1: degree (weighted) + count histogram by col ----
__global__ void k_edge1(const int* __restrict__ ei, const float* __restrict__ ew,
                        float* __restrict__ deg, int* __restrict__ cnt) {
  int e = blockIdx.x * 256 + threadIdx.x;
  if (e < EE) {
    int c = ei[EE + e];
    atomicAdd(deg + c, ew[e]);
    atomicAdd(cnt + c, 1);
  }
}

__global__ void k_dinv(const float* __restrict__ deg, float* __restrict__ dinv) {
  int i = blockIdx.x * 256 + threadIdx.x;
  if (i < NN) {
    float d = deg[i];
    dinv[i] = d > 0.f ? rsqrtf(d) : 0.f;
  }
}

// ---- scan stage 1 ----
__global__ __launch_bounds__(256) void k_scan_part(const int* __restrict__ cnt,
                                                   int* __restrict__ part) {
  int b = blockIdx.x, t = threadIdx.x, lane = t & 63, wid = t >> 6;
  int base = b * NCHUNK + t * 4;
  int s = 0;
  if (base + 3 < NN) {
    i32x4 v = *(const i32x4*)(cnt + base);
    s = v[0] + v[1] + v[2] + v[3];
  } else {
    for (int j = 0; j < 4; ++j) if (base + j < NN) s += cnt[base + j];
  }
  for (int d = 32; d > 0; d >>= 1) s += __shfl_down(s, d);
  __shared__ int wsum[4];
  if (lane == 0) wsum[wid] = s;
  __syncthreads();
  if (t == 0) part[b] = wsum[0] + wsum[1] + wsum[2] + wsum[3];
}

// ---- scan stage 2 ----
__global__ void k_scan_mid(int* __restrict__ part, int* __restrict__ rowptr) {
  __shared__ int sm[128];
  int t = threadIdx.x;
  int v = (t < NBLK) ? part[t] : 0;
  sm[t] = v;
  __syncthreads();
  for (int off = 1; off < 128; off <<= 1) {
    int a = sm[t];
    int b = (t >= off) ? sm[t - off] : 0;
    __syncthreads();
    sm[t] = a + b;
    __syncthreads();
  }
  if (t < NBLK) part[t] = (t == 0) ? 0 : sm[t - 1];
  if (t == 127) rowptr[NN] = sm[127];
}

// ---- scan stage 3 ----
__global__ __launch_bounds__(256) void k_scan_final(const int* __restrict__ cnt,
    const int* __restrict__ part, int* __restrict__ rowptr, int* __restrict__ cursor) {
  int b = blockIdx.x, t = threadIdx.x, lane = t & 63, wid = t >> 6;
  int base = b * NCHUNK + t * 4;
  int c0 = 0, c1 = 0, c2 = 0, c3 = 0;
  if (base + 3 < NN) {
    i32x4 v = *(const i32x4*)(cnt + base);
    c0 = v[0]; c1 = v[1]; c2 = v[2]; c3 = v[3];
  } else {
    if (base < NN) c0 = cnt[base];
    if (base + 1 < NN) c1 = cnt[base + 1];
    if (base + 2 < NN) c2 = cnt[base + 2];
    if (base + 3 < NN) c3 = cnt[base + 3];
  }
  int s = c0 + c1 + c2 + c3;
  int v = s;
  for (int d = 1; d < 64; d <<= 1) {
    int u = __shfl_up(v, d);
    if (lane >= d) v += u;
  }
  __shared__ int wsum[4];
  if (lane == 63) wsum[wid] = v;
  __syncthreads();
  int woff = 0;
  for (int w = 0; w < wid; ++w) woff += wsum[w];
  int excl = part[b] + woff + (v - s);
  if (base < NN)     { rowptr[base]     = excl; cursor[base]     = excl; excl += c0; }
  if (base + 1 < NN) { rowptr[base + 1] = excl; cursor[base + 1] = excl; excl += c1; }
  if (base + 2 < NN) { rowptr[base + 2] = excl; cursor[base + 2] = excl; excl += c2; }
  if (base + 3 < NN) { rowptr[base + 3] = excl; cursor[base + 3] = excl; }
}

// ---- edge pass 2: bucket (row, norm) by col ----
__global__ void k_edge2(const int* __restrict__ ei, const float* __restrict__ ew,
                        const float* __restrict__ dinv, int* __restrict__ cursor,
                        int* __restrict__ srow, float* __restrict__ snorm) {
  int e = blockIdx.x * 256 + threadIdx.x;
  if (e < EE) {
    int r = ei[e], c = ei[EE + e];
    float nrm = dinv[r] * ew[e] * dinv[c];
    int pos = atomicAdd(cursor + c, 1);
    srow[pos] = r;
    snorm[pos] = nrm;
  }
}

// ---- dual GEMM, LDS-staged weights. 512 threads = 8 waves x 16 rows.
// hl -> tmpb (bf16), hgemm -> hg (bf16). APPLY=1: input is bf16 pre-BN h,
// apply per-column scale/bias + ReLU before use. In-place tmpb is row-safe.
template<int APPLY>
__global__ __launch_bounds__(512) void k_dualgemm(const void* __restrict__ Hv,
    const short* __restrict__ Wl, const short* __restrict__ Wg,
    const float* __restrict__ sb, unsigned short* __restrict__ tmpo,
    unsigned short* __restrict__ hg) {
  __shared__ short lw[2 * DD * DD];   // 64 KB
  int tid = threadIdx.x;

  // stage: 4096 16B-units; swizzled global source -> linear LDS
#pragma unroll
  for (int c = 0; c < 8; ++c) {
    int q = c * 512 + tid;
    int region = q >> 11;            // 0 = Wl, 1 = Wg
    int row = (q >> 4) & 127;
    int u = q & 15;
    const short* src = (region ? Wg : Wl) + row * DD + ((u ^ (row & 7)) * 8);
    *(bf16x8*)(lw + q * 8) = *(const bf16x8*)src;
  }

  int lane = tid & 63, wv = tid >> 6;
  int row0 = blockIdx.x * 128 + wv * 16;
  int m = lane & 15, g = lane >> 4;

  bf16x8 hb[4];
  if (row0 < NN) {
#pragma unroll
    for (int s = 0; s < 4; ++s) {
      float f[8];
      if (APPLY) {
        const unsigned short* H = (const unsigned short*)Hv;
        bf16x8 hv = *(const bf16x8*)(H + (size_t)(row0 + m) * DD + s * 32 + g * 8);
#pragma unroll
        for (int k2 = 0; k2 < 8; ++k2)
          f[k2] = bfbits2f(((unsigned)(unsigned short)hv[k2]) << 16);
      } else {
        const float* H = (const float*)Hv;
        f32x4 v0 = *(const f32x4*)(H + (size_t)(row0 + m) * DD + s * 32 + g * 8);
        f32x4 v1 = *(const f32x4*)(H + (size_t)(row0 + m) * DD + s * 32 + g * 8 + 4);
#pragma unroll
        for (int k2 = 0; k2 < 4; ++k2) { f[k2] = v0[k2]; f[k2 + 4] = v1[k2]; }
      }
      if (APPLY) {
        f32x4 sc0 = *(const f32x4*)(sb + s * 32 + g * 8);
        f32x4 sc1 = *(const f32x4*)(sb + s * 32 + g * 8 + 4);
        f32x4 bi0 = *(const f32x4*)(sb + DD + s * 32 + g * 8);
        f32x4 bi1 = *(const f32x4*)(sb + DD + s * 32 + g * 8 + 4);
#pragma unroll
        for (int k2 = 0; k2 < 4; ++k2) {
          f[k2]     = fmaxf(f[k2]     * sc0[k2] + bi0[k2], 0.f);
          f[k2 + 4] = fmaxf(f[k2 + 4] * sc1[k2] + bi1[k2], 0.f);
        }
      }
      bf16x8 tt;
#pragma unroll
      for (int k2 = 0; k2 < 8; ++k2) tt[k2] = f2bf(f[k2]);
      hb[s] = tt;
    }
  }

  __syncthreads();
  if (row0 >= NN) return;

  int mx = m & 7;
#pragma unroll
  for (int t = 0; t < 8; ++t) {
    f32x4 accl; accl[0] = 0.f; accl[1] = 0.f; accl[2] = 0.f; accl[3] = 0.f;
    f32x4 accg = accl;
#pragma unroll
    for (int s = 0; s < 4; ++s) {
      int u = (s * 4 + g) ^ mx;
      int base = (t * 16 + m) * DD + u * 8;
      bf16x8 wlf = *(const bf16x8*)(lw + base);
      bf16x8 wgf = *(const bf16x8*)(lw + DD * DD + base);
      accl = __builtin_amdgcn_mfma_f32_16x16x32_bf16(wlf, hb[s], accl, 0, 0, 0);
      accg = __builtin_amdgcn_mfma_f32_16x16x32_bf16(wgf, hb[s], accg, 0, 0, 0);
    }
    size_t r = (size_t)(row0 + m);
    bf16x4 l4, h4;
    l4[0] = f2bf(accl[0]); l4[1] = f2bf(accl[1]); l4[2] = f2bf(accl[2]); l4[3] = f2bf(accl[3]);
    h4[0] = f2bf(accg[0]); h4[1] = f2bf(accg[1]); h4[2] = f2bf(accg[2]); h4[3] = f2bf(accg[3]);
    *(bf16x4*)(tmpo + r * DD + t * 16 + g * 4) = l4;
    *(bf16x4*)(hg + r * DD + t * 16 + g * 4) = h4;
  }
}

// ---- aggregation: one wave per node, NO cross-wave coupling (proven 47.7us shape).
// tmpb[node] (bf16) += sum norm * hg[srcrow] (bf16 gather, one u32/lane).
__global__ __launch_bounds__(256) void k_agg(const int* __restrict__ rowptr,
    const int* __restrict__ srow, const float* __restrict__ snorm,
    const unsigned int* __restrict__ hgu, unsigned int* __restrict__ tmpu) {
  int node = (blockIdx.x * 256 + (int)threadIdx.x) >> 6;
  int lane = threadIdx.x & 63;
  if (node >= NN) return;
  node = __builtin_amdgcn_readfirstlane(node);
  int beg = rowptr[node], end = rowptr[node + 1];
  float ax = 0.f, ay = 0.f;
  for (int j = beg; j < end; ++j) {
    int r = srow[j];
    float w = snorm[j];
    unsigned u = hgu[r * 64 + lane];      // 2 bf16: cols 2*lane, 2*lane+1
    ax += w * bfbits2f(u << 16);
    ay += w * bfbits2f(u & 0xffff0000u);
  }
  unsigned* tp = tmpu + (size_t)node * 64 + lane;
  unsigned hl = *tp;
  float t0 = bfbits2f(hl << 16) + ax;
  float t1 = bfbits2f(hl & 0xffff0000u) + ay;
  unsigned p0 = (unsigned)(unsigned short)f2bf(t0);
  unsigned p1 = (unsigned)(unsigned short)f2bf(t1);
  *tp = p0 | (p1 << 16);
}

// ---- BN stats over bf16 h: 2000 blocks x 50 rows, coalesced u32x2, LDS reduce ----
__global__ __launch_bounds__(256) void k_bnstats(const unsigned int* __restrict__ h,
    float* __restrict__ psum, float* __restrict__ pss) {
  int b = blockIdx.x, t = threadIdx.x;
  int cg = t & 31, rs = t >> 5;          // column group (4 cols), row slice (0..7)
  f32x4 s; s[0] = 0.f; s[1] = 0.f; s[2] = 0.f; s[3] = 0.f;
  f32x4 q = s;
  int r0 = b * RPB;
  for (int r = r0 + rs; r < r0 + RPB; r += 8) {
    u32x2 u = *(const u32x2*)(h + (size_t)r * 64 + cg * 2);
    f32x4 v;
    v[0] = bfbits2f(u[0] << 16); v[1] = bfbits2f(u[0] & 0xffff0000u);
    v[2] = bfbits2f(u[1] << 16); v[3] = bfbits2f(u[1] & 0xffff0000u);
    s += v; q += v * v;
  }
  __shared__ f32x4 ls[8][32], lq[8][32];
  ls[rs][cg] = s; lq[rs][cg] = q;
  __syncthreads();
  if (t < 32) {
    f32x4 a = ls[0][t], qq = lq[0][t];
#pragma unroll
    for (int k = 1; k < 8; ++k) { a += ls[k][t]; qq += lq[k][t]; }
#pragma unroll
    for (int c = 0; c < 4; ++c) {
      psum[(t * 4 + c) * NPB + b] = a[c];
      pss [(t * 4 + c) * NPB + b] = qq[c];
    }
  }
}

// ---- reduce partials -> per-column scale/bias (folds gamma/beta/rsqrt) ----
__global__ __launch_bounds__(256) void k_bnreduce(const float* __restrict__ psum,
    const float* __restrict__ pss, const float* __restrict__ gamma,
    const float* __restrict__ beta, float* __restrict__ sb) {
  int col = blockIdx.x, t = threadIdx.x;
  float s = 0.f, q = 0.f;
  for (int i = t; i < NPB; i += 256) { s += psum[col * NPB + i]; q += pss[col * NPB + i]; }
  for (int d = 32; d > 0; d >>= 1) { s += __shfl_down(s, d); q += __shfl_down(q, d); }
  __shared__ float lws[4], lwq[4];
  int wid = t >> 6, lane = t & 63;
  if (lane == 0) { lws[wid] = s; lwq[wid] = q; }
  __syncthreads();
  if (t == 0) {
    float S = lws[0] + lws[1] + lws[2] + lws[3];
    float Q = lwq[0] + lwq[1] + lwq[2] + lwq[3];
    float mean = S * (1.f / NN);
    float var = Q * (1.f / NN) - mean * mean;
    float sc = rsqrtf(var + EPSV) * gamma[col];
    sb[col] = sc;
    sb[DD + col] = beta[col] - mean * sc;
  }
}

// ---- final BN apply: bf16 h -> f32 out, x*scale + bias (no relu) ----
__global__ void k_bnapply(const unsigned int* __restrict__ hb, const float* __restrict__ sb,
                          float* __restrict__ out) {
  int i = blockIdx.x * 256 + threadIdx.x;   // over NN*DD/4
  if (i >= NN * DD / 4) return;
  int d0 = (i * 4) & (DD - 1);
  u32x2 u = *(const u32x2*)(hb + i * 2);
  f32x4 o;
  o[0] = bfbits2f(u[0] << 16)          * sb[d0]     + sb[DD + d0];
  o[1] = bfbits2f(u[0] & 0xffff0000u)  * sb[d0 + 1] + sb[DD + d0 + 1];
  o[2] = bfbits2f(u[1] << 16)          * sb[d0 + 2] + sb[DD + d0 + 2];
  o[3] = bfbits2f(u[1] & 0xffff0000u)  * sb[d0 + 3] + sb[DD + d0 + 3];
  ((f32x4*)out)[i] = o;
}

extern "C" void kernel_launch(void* const* d_in, const int* in_sizes, int n_in,
                              void* d_out, int out_size, void* d_ws, size_t ws_size,
                              hipStream_t stream) {
  const float* x     = (const float*)d_in[0];
  const int*   ei    = (const int*)d_in[1];
  const float* ew    = (const float*)d_in[2];
  const float* lin_w = (const float*)d_in[3];
  const float* gcn_w = (const float*)d_in[4];
  const float* gamma = (const float*)d_in[5];
  const float* beta  = (const float*)d_in[6];
  float* out = (float*)d_out;

  char* ws = (char*)d_ws;
  size_t off = 0;
  auto alloc = [&](size_t bytes) -> void* {
    void* p = ws + off;
    off += (bytes + 255) & ~(size_t)255;
    return p;
  };
  unsigned short* hg   = (unsigned short*)alloc((size_t)NN * DD * 2);  // bf16
  unsigned short* tmpb = (unsigned short*)alloc((size_t)NN * DD * 2);  // bf16 h
  float* snorm  = (float*)alloc((size_t)EE * 4);
  int*   srow   = (int*)alloc((size_t)EE * 4);
  float* deg    = (float*)alloc((size_t)NN * 4);
  float* dinv   = (float*)alloc((size_t)NN * 4);
  int*   rowptr = (int*)alloc((size_t)(NN + 1) * 4);
  int*   cursor = (int*)alloc((size_t)NN * 4);
  int*   cnt    = (int*)alloc((size_t)NN * 4);
  int*   part   = (int*)alloc((size_t)NBLK * 4);
  short* wbf    = (short*)alloc((size_t)2 * NDEPTH * DD * DD * 2);
  float* psum   = (float*)alloc((size_t)DD * NPB * 4);
  float* pss    = (float*)alloc((size_t)DD * NPB * 4);
  float* sb     = (float*)alloc((size_t)2 * DD * 4);

  hipMemsetAsync(deg, 0, (size_t)NN * 4, stream);
  hipMemsetAsync(cnt, 0, (size_t)NN * 4, stream);

  k_convert_w<<<(NDEPTH * DD * DD + 255) / 256, 256, 0, stream>>>(lin_w, gcn_w, wbf);
  k_edge1<<<(EE + 255) / 256, 256, 0, stream>>>(ei, ew, deg, cnt);
  k_dinv<<<(NN + 255) / 256, 256, 0, stream>>>(deg, dinv);
  k_scan_part<<<NBLK, 256, 0, stream>>>(cnt, part);
  k_scan_mid<<<1, 128, 0, stream>>>(part, rowptr);
  k_scan_final<<<NBLK, 256, 0, stream>>>(cnt, part, rowptr, cursor);
  k_edge2<<<(EE + 255) / 256, 256, 0, stream>>>(ei, ew, dinv, cursor, srow, snorm);

  const short* Wl0 = wbf;
  const short* Wg0 = wbf + (size_t)NDEPTH * DD * DD;
  const short* Wl1 = wbf + (size_t)DD * DD;
  const short* Wg1 = wbf + (size_t)NDEPTH * DD * DD + (size_t)DD * DD;
  const int GEMMBLK = (NN + 127) / 128;   // 782

  // layer 0
  k_dualgemm<0><<<GEMMBLK, 512, 0, stream>>>(x, Wl0, Wg0, sb, tmpb, hg);
  k_agg<<<(NN + 3) / 4, 256, 0, stream>>>(rowptr, srow, snorm, (const unsigned int*)hg,
                                          (unsigned int*)tmpb);
  k_bnstats<<<NPB, 256, 0, stream>>>((const unsigned int*)tmpb, psum, pss);
  k_bnreduce<<<DD, 256, 0, stream>>>(psum, pss, gamma, beta, sb);

  // layer 1 (BN+ReLU folded into H load; in-place tmpb is row-safe)
  k_dualgemm<1><<<GEMMBLK, 512, 0, stream>>>(tmpb, Wl1, Wg1, sb, tmpb, hg);
  k_agg<<<(NN + 3) / 4, 256, 0, stream>>>(rowptr, srow, snorm, (const unsigned int*)hg,
                                          (unsigned int*)tmpb);
  k_bnstats<<<NPB, 256, 0, stream>>>((const unsigned int*)tmpb, psum, pss);
  k_bnreduce<<<DD, 256, 0, stream>>>(psum, pss, gamma + DD, beta + DD, sb);
  k_bnapply<<<(NN * DD / 4 + 255) / 256, 256, 0, stream>>>((const unsigned int*)tmpb, sb, out);
}

// Round 12
// 242.394 us; speedup vs baseline: 1.5260x; 1.1767x over previous
//
#include <hip/hip_runtime.h>
#include <hip/hip_bf16.h>

#define NN 100000
#define EE 500000
#define DD 128
#define NDEPTH 2
#define EPSV 1e-5f
#define NCHUNK 1024
#define NBLK ((NN + NCHUNK - 1) / NCHUNK)   // 98
#define NPB 2000     // bnstats blocks
#define RPB 50       // rows per bnstats block

typedef __attribute__((ext_vector_type(4))) float f32x4;
typedef __attribute__((ext_vector_type(4))) int i32x4;
typedef __attribute__((ext_vector_type(2))) unsigned int u32x2;
typedef __attribute__((ext_vector_type(8))) short bf16x8;
typedef __attribute__((ext_vector_type(4))) short bf16x4;

static __device__ __forceinline__ short f2bf(float x) {
  union { float f; unsigned u; } v; v.f = x;
  unsigned r = v.u + 0x7fffu + ((v.u >> 16) & 1u);  // round-to-nearest-even
  return (short)(r >> 16);
}
static __device__ __forceinline__ float bfbits2f(unsigned hi16) {
  union { unsigned u; float f; } v; v.u = hi16;
  return v.f;
}

// ---- convert both weight tensors to bf16 once ----
__global__ void k_convert_w(const float* __restrict__ lw, const float* __restrict__ gw,
                            short* __restrict__ wbf) {
  int i = blockIdx.x * 256 + threadIdx.x;
  if (i < NDEPTH * DD * DD) {
    wbf[i] = f2bf(lw[i]);
    wbf[NDEPTH * DD * DD + i] = f2bf(gw[i]);
  }
}

// ---- edge pass 1: ONE u64 atomic per edge: (count<<44) | fixed32(weight) ----
__global__ void k_edge1(const int* __restrict__ ei, const float* __restrict__ ew,
                        unsigned long long* __restrict__ dc) {
  int e = blockIdx.x * 256 + threadIdx.x;
  if (e < EE) {
    int c = ei[EE + e];
    unsigned long long pack = (1ULL << 44) |
        (unsigned long long)(ew[e] * 4294967296.0f + 0.5f);
    atomicAdd(dc + c, pack);
  }
}

// ---- unpack: dinv + int count (for the scan) ----
__global__ void k_dinv(const unsigned long long* __restrict__ dc,
                       float* __restrict__ dinv, int* __restrict__ cnt) {
  int i = blockIdx.x * 256 + threadIdx.x;
  if (i < NN) {
    unsigned long long v = dc[i];
    cnt[i] = (int)(v >> 44);
    float deg = (float)(v & ((1ULL << 44) - 1)) * (1.0f / 4294967296.0f);
    dinv[i] = deg > 0.f ? rsqrtf(deg) : 0.f;
  }
}

// ---- scan stage 1 ----
__global__ __launch_bounds__(256) void k_scan_part(const int* __restrict__ cnt,
                                                   int* __restrict__ part) {
  int b = blockIdx.x, t = threadIdx.x, lane = t & 63, wid = t >> 6;
  int base = b * NCHUNK + t * 4;
  int s = 0;
  if (base + 3 < NN) {
    i32x4 v = *(const i32x4*)(cnt + base);
    s = v[0] + v[1] + v[2] + v[3];
  } else {
    for (int j = 0; j < 4; ++j) if (base + j < NN) s += cnt[base + j];
  }
  for (int d = 32; d > 0; d >>= 1) s += __shfl_down(s, d);
  __shared__ int wsum[4];
  if (lane == 0) wsum[wid] = s;
  __syncthreads();
  if (t == 0) part[b] = wsum[0] + wsum[1] + wsum[2] + wsum[3];
}

// ---- scan stage 2 ----
__global__ void k_scan_mid(int* __restrict__ part, int* __restrict__ rowptr) {
  __shared__ int sm[128];
  int t = threadIdx.x;
  int v = (t < NBLK) ? part[t] : 0;
  sm[t] = v;
  __syncthreads();
  for (int off = 1; off < 128; off <<= 1) {
    int a = sm[t];
    int b = (t >= off) ? sm[t - off] : 0;
    __syncthreads();
    sm[t] = a + b;
    __syncthreads();
  }
  if (t < NBLK) part[t] = (t == 0) ? 0 : sm[t - 1];
  if (t == 127) rowptr[NN] = sm[127];
}

// ---- scan stage 3 ----
__global__ __launch_bounds__(256) void k_scan_final(const int* __restrict__ cnt,
    const int* __restrict__ part, int* __restrict__ rowptr, int* __restrict__ cursor) {
  int b = blockIdx.x, t = threadIdx.x, lane = t & 63, wid = t >> 6;
  int base = b * NCHUNK + t * 4;
  int c0 = 0, c1 = 0, c2 = 0, c3 = 0;
  if (base + 3 < NN) {
    i32x4 v = *(const i32x4*)(cnt + base);
    c0 = v[0]; c1 = v[1]; c2 = v[2]; c3 = v[3];
  } else {
    if (base < NN) c0 = cnt[base];
    if (base + 1 < NN) c1 = cnt[base + 1];
    if (base + 2 < NN) c2 = cnt[base + 2];
    if (base + 3 < NN) c3 = cnt[base + 3];
  }
  int s = c0 + c1 + c2 + c3;
  int v = s;
  for (int d = 1; d < 64; d <<= 1) {
    int u = __shfl_up(v, d);
    if (lane >= d) v += u;
  }
  __shared__ int wsum[4];
  if (lane == 63) wsum[wid] = v;
  __syncthreads();
  int woff = 0;
  for (int w = 0; w < wid; ++w) woff += wsum[w];
  int excl = part[b] + woff + (v - s);
  if (base < NN)     { rowptr[base]     = excl; cursor[base]     = excl; excl += c0; }
  if (base + 1 < NN) { rowptr[base + 1] = excl; cursor[base + 1] = excl; excl += c1; }
  if (base + 2 < NN) { rowptr[base + 2] = excl; cursor[base + 2] = excl; excl += c2; }
  if (base + 3 < NN) { rowptr[base + 3] = excl; cursor[base + 3] = excl; }
}

// ---- edge pass 2: bucket (row, norm) by col ----
__global__ void k_edge2(const int* __restrict__ ei, const float* __restrict__ ew,
                        const float* __restrict__ dinv, int* __restrict__ cursor,
                        int* __restrict__ srow, float* __restrict__ snorm) {
  int e = blockIdx.x * 256 + threadIdx.x;
  if (e < EE) {
    int r = ei[e], c = ei[EE + e];
    float nrm = dinv[r] * ew[e] * dinv[c];
    int pos = atomicAdd(cursor + c, 1);
    srow[pos] = r;
    snorm[pos] = nrm;
  }
}

// ---- dual GEMM, LDS-staged weights. 512 threads = 8 waves x 16 rows.
// hl -> tmpb (bf16), hgemm -> hg (bf16). APPLY=1: input is bf16 pre-BN h,
// apply per-column scale/bias + ReLU before use. In-place tmpb is row-safe.
template<int APPLY>
__global__ __launch_bounds__(512) void k_dualgemm(const void* __restrict__ Hv,
    const short* __restrict__ Wl, const short* __restrict__ Wg,
    const float* __restrict__ sb, unsigned short* __restrict__ tmpo,
    unsigned short* __restrict__ hg) {
  __shared__ short lw[2 * DD * DD];   // 64 KB
  int tid = threadIdx.x;

  // stage: 4096 16B-units; swizzled global source -> linear LDS
#pragma unroll
  for (int c = 0; c < 8; ++c) {
    int q = c * 512 + tid;
    int region = q >> 11;            // 0 = Wl, 1 = Wg
    int row = (q >> 4) & 127;
    int u = q & 15;
    const short* src = (region ? Wg : Wl) + row * DD + ((u ^ (row & 7)) * 8);
    *(bf16x8*)(lw + q * 8) = *(const bf16x8*)src;
  }

  int lane = tid & 63, wv = tid >> 6;
  int row0 = blockIdx.x * 128 + wv * 16;
  int m = lane & 15, g = lane >> 4;

  bf16x8 hb[4];
  if (row0 < NN) {
#pragma unroll
    for (int s = 0; s < 4; ++s) {
      float f[8];
      if (APPLY) {
        const unsigned short* H = (const unsigned short*)Hv;
        bf16x8 hv = *(const bf16x8*)(H + (size_t)(row0 + m) * DD + s * 32 + g * 8);
#pragma unroll
        for (int k2 = 0; k2 < 8; ++k2)
          f[k2] = bfbits2f(((unsigned)(unsigned short)hv[k2]) << 16);
      } else {
        const float* H = (const float*)Hv;
        f32x4 v0 = *(const f32x4*)(H + (size_t)(row0 + m) * DD + s * 32 + g * 8);
        f32x4 v1 = *(const f32x4*)(H + (size_t)(row0 + m) * DD + s * 32 + g * 8 + 4);
#pragma unroll
        for (int k2 = 0; k2 < 4; ++k2) { f[k2] = v0[k2]; f[k2 + 4] = v1[k2]; }
      }
      if (APPLY) {
        f32x4 sc0 = *(const f32x4*)(sb + s * 32 + g * 8);
        f32x4 sc1 = *(const f32x4*)(sb + s * 32 + g * 8 + 4);
        f32x4 bi0 = *(const f32x4*)(sb + DD + s * 32 + g * 8);
        f32x4 bi1 = *(const f32x4*)(sb + DD + s * 32 + g * 8 + 4);
#pragma unroll
        for (int k2 = 0; k2 < 4; ++k2) {
          f[k2]     = fmaxf(f[k2]     * sc0[k2] + bi0[k2], 0.f);
          f[k2 + 4] = fmaxf(f[k2 + 4] * sc1[k2] + bi1[k2], 0.f);
        }
      }
      bf16x8 tt;
#pragma unroll
      for (int k2 = 0; k2 < 8; ++k2) tt[k2] = f2bf(f[k2]);
      hb[s] = tt;
    }
  }

  __syncthreads();
  if (row0 >= NN) return;

  int mx = m & 7;
#pragma unroll
  for (int t = 0; t < 8; ++t) {
    f32x4 accl; accl[0] = 0.f; accl[1] = 0.f; accl[2] = 0.f; accl[3] = 0.f;
    f32x4 accg = accl;
#pragma unroll
    for (int s = 0; s < 4; ++s) {
      int u = (s * 4 + g) ^ mx;
      int base = (t * 16 + m) * DD + u * 8;
      bf16x8 wlf = *(const bf16x8*)(lw + base);
      bf16x8 wgf = *(const bf16x8*)(lw + DD * DD + base);
      accl = __builtin_amdgcn_mfma_f32_16x16x32_bf16(wlf, hb[s], accl, 0, 0, 0);
      accg = __builtin_amdgcn_mfma_f32_16x16x32_bf16(wgf, hb[s], accg, 0, 0, 0);
    }
    size_t r = (size_t)(row0 + m);
    bf16x4 l4, h4;
    l4[0] = f2bf(accl[0]); l4[1] = f2bf(accl[1]); l4[2] = f2bf(accl[2]); l4[3] = f2bf(accl[3]);
    h4[0] = f2bf(accg[0]); h4[1] = f2bf(accg[1]); h4[2] = f2bf(accg[2]); h4[3] = f2bf(accg[3]);
    *(bf16x4*)(tmpo + r * DD + t * 16 + g * 4) = l4;
    *(bf16x4*)(hg + r * DD + t * 16 + g * 4) = h4;
  }
}

// ---- aggregation: one wave per node, 4-way edge unroll (4 concurrent gather chains).
// tmpb[node] (bf16) += sum norm * hg[srcrow] (bf16 gather, one u32/lane).
__global__ __launch_bounds__(256) void k_agg(const int* __restrict__ rowptr,
    const int* __restrict__ srow, const float* __restrict__ snorm,
    const unsigned int* __restrict__ hgu, unsigned int* __restrict__ tmpu) {
  int node = (blockIdx.x * 256 + (int)threadIdx.x) >> 6;
  int lane = threadIdx.x & 63;
  if (node >= NN) return;
  node = __builtin_amdgcn_readfirstlane(node);
  int beg = rowptr[node], end = rowptr[node + 1];
  float ax = 0.f, ay = 0.f;
  int j = beg;
  for (; j + 3 < end; j += 4) {
    int r0 = srow[j], r1 = srow[j + 1], r2 = srow[j + 2], r3 = srow[j + 3];
    float w0 = snorm[j], w1 = snorm[j + 1], w2 = snorm[j + 2], w3 = snorm[j + 3];
    unsigned u0 = hgu[r0 * 64 + lane];
    unsigned u1 = hgu[r1 * 64 + lane];
    unsigned u2 = hgu[r2 * 64 + lane];
    unsigned u3 = hgu[r3 * 64 + lane];
    ax += w0 * bfbits2f(u0 << 16) + w1 * bfbits2f(u1 << 16)
        + w2 * bfbits2f(u2 << 16) + w3 * bfbits2f(u3 << 16);
    ay += w0 * bfbits2f(u0 & 0xffff0000u) + w1 * bfbits2f(u1 & 0xffff0000u)
        + w2 * bfbits2f(u2 & 0xffff0000u) + w3 * bfbits2f(u3 & 0xffff0000u);
  }
  for (; j < end; ++j) {
    int r = srow[j];
    float w = snorm[j];
    unsigned u = hgu[r * 64 + lane];
    ax += w * bfbits2f(u << 16);
    ay += w * bfbits2f(u & 0xffff0000u);
  }
  unsigned* tp = tmpu + (size_t)node * 64 + lane;
  unsigned hl = *tp;
  float t0 = bfbits2f(hl << 16) + ax;
  float t1 = bfbits2f(hl & 0xffff0000u) + ay;
  unsigned p0 = (unsigned)(unsigned short)f2bf(t0);
  unsigned p1 = (unsigned)(unsigned short)f2bf(t1);
  *tp = p0 | (p1 << 16);
}

// ---- BN stats over bf16 h: 2000 blocks x 50 rows, coalesced u32x2, LDS reduce ----
__global__ __launch_bounds__(256) void k_bnstats(const unsigned int* __restrict__ h,
    float* __restrict__ psum, float* __restrict__ pss) {
  int b = blockIdx.x, t = threadIdx.x;
  int cg = t & 31, rs = t >> 5;          // column group (4 cols), row slice (0..7)
  f32x4 s; s[0] = 0.f; s[1] = 0.f; s[2] = 0.f; s[3] = 0.f;
  f32x4 q = s;
  int r0 = b * RPB;
  for (int r = r0 + rs; r < r0 + RPB; r += 8) {
    u32x2 u = *(const u32x2*)(h + (size_t)r * 64 + cg * 2);
    f32x4 v;
    v[0] = bfbits2f(u[0] << 16); v[1] = bfbits2f(u[0] & 0xffff0000u);
    v[2] = bfbits2f(u[1] << 16); v[3] = bfbits2f(u[1] & 0xffff0000u);
    s += v; q += v * v;
  }
  __shared__ f32x4 ls[8][32], lq[8][32];
  ls[rs][cg] = s; lq[rs][cg] = q;
  __syncthreads();
  if (t < 32) {
    f32x4 a = ls[0][t], qq = lq[0][t];
#pragma unroll
    for (int k = 1; k < 8; ++k) { a += ls[k][t]; qq += lq[k][t]; }
#pragma unroll
    for (int c = 0; c < 4; ++c) {
      psum[(t * 4 + c) * NPB + b] = a[c];
      pss [(t * 4 + c) * NPB + b] = qq[c];
    }
  }
}

// ---- reduce partials -> per-column scale/bias (folds gamma/beta/rsqrt) ----
__global__ __launch_bounds__(256) void k_bnreduce(const float* __restrict__ psum,
    const float* __restrict__ pss, const float* __restrict__ gamma,
    const float* __restrict__ beta, float* __restrict__ sb) {
  int col = blockIdx.x, t = threadIdx.x;
  float s = 0.f, q = 0.f;
  for (int i = t; i < NPB; i += 256) { s += psum[col * NPB + i]; q += pss[col * NPB + i]; }
  for (int d = 32; d > 0; d >>= 1) { s += __shfl_down(s, d); q += __shfl_down(q, d); }
  __shared__ float lws[4], lwq[4];
  int wid = t >> 6, lane = t & 63;
  if (lane == 0) { lws[wid] = s; lwq[wid] = q; }
  __syncthreads();
  if (t == 0) {
    float S = lws[0] + lws[1] + lws[2] + lws[3];
    float Q = lwq[0] + lwq[1] + lwq[2] + lwq[3];
    float mean = S * (1.f / NN);
    float var = Q * (1.f / NN) - mean * mean;
    float sc = rsqrtf(var + EPSV) * gamma[col];
    sb[col] = sc;
    sb[DD + col] = beta[col] - mean * sc;
  }
}

// ---- final BN apply: bf16 h -> f32 out, x*scale + bias (no relu) ----
__global__ void k_bnapply(const unsigned int* __restrict__ hb, const float* __restrict__ sb,
                          float* __restrict__ out) {
  int i = blockIdx.x * 256 + threadIdx.x;   // over NN*DD/4
  if (i >= NN * DD / 4) return;
  int d0 = (i * 4) & (DD - 1);
  u32x2 u = *(const u32x2*)(hb + i * 2);
  f32x4 o;
  o[0] = bfbits2f(u[0] << 16)          * sb[d0]     + sb[DD + d0];
  o[1] = bfbits2f(u[0] & 0xffff0000u)  * sb[d0 + 1] + sb[DD + d0 + 1];
  o[2] = bfbits2f(u[1] << 16)          * sb[d0 + 2] + sb[DD + d0 + 2];
  o[3] = bfbits2f(u[1] & 0xffff0000u)  * sb[d0 + 3] + sb[DD + d0 + 3];
  ((f32x4*)out)[i] = o;
}

extern "C" void kernel_launch(void* const* d_in, const int* in_sizes, int n_in,
                              void* d_out, int out_size, void* d_ws, size_t ws_size,
                              hipStream_t stream) {
  const float* x     = (const float*)d_in[0];
  const int*   ei    = (const int*)d_in[1];
  const float* ew    = (const float*)d_in[2];
  const float* lin_w = (const float*)d_in[3];
  const float* gcn_w = (const float*)d_in[4];
  const float* gamma = (const float*)d_in[5];
  const float* beta  = (const float*)d_in[6];
  float* out = (float*)d_out;

  char* ws = (char*)d_ws;
  size_t off = 0;
  auto alloc = [&](size_t bytes) -> void* {
    void* p = ws + off;
    off += (bytes + 255) & ~(size_t)255;
    return p;
  };
  unsigned short* hg   = (unsigned short*)alloc((size_t)NN * DD * 2);  // bf16
  unsigned short* tmpb = (unsigned short*)alloc((size_t)NN * DD * 2);  // bf16 h
  float* snorm  = (float*)alloc((size_t)EE * 4);
  int*   srow   = (int*)alloc((size_t)EE * 4);
  unsigned long long* dc = (unsigned long long*)alloc((size_t)NN * 8);
  float* dinv   = (float*)alloc((size_t)NN * 4);
  int*   rowptr = (int*)alloc((size_t)(NN + 1) * 4);
  int*   cursor = (int*)alloc((size_t)NN * 4);
  int*   cnt    = (int*)alloc((size_t)NN * 4);
  int*   part   = (int*)alloc((size_t)NBLK * 4);
  short* wbf    = (short*)alloc((size_t)2 * NDEPTH * DD * DD * 2);
  float* psum   = (float*)alloc((size_t)DD * NPB * 4);
  float* pss    = (float*)alloc((size_t)DD * NPB * 4);
  float* sb     = (float*)alloc((size_t)2 * DD * 4);

  hipMemsetAsync(dc, 0, (size_t)NN * 8, stream);

  k_convert_w<<<(NDEPTH * DD * DD + 255) / 256, 256, 0, stream>>>(lin_w, gcn_w, wbf);
  k_edge1<<<(EE + 255) / 256, 256, 0, stream>>>(ei, ew, dc);
  k_dinv<<<(NN + 255) / 256, 256, 0, stream>>>(dc, dinv, cnt);
  k_scan_part<<<NBLK, 256, 0, stream>>>(cnt, part);
  k_scan_mid<<<1, 128, 0, stream>>>(part, rowptr);
  k_scan_final<<<NBLK, 256, 0, stream>>>(cnt, part, rowptr, cursor);
  k_edge2<<<(EE + 255) / 256, 256, 0, stream>>>(ei, ew, dinv, cursor, srow, snorm);

  const short* Wl0 = wbf;
  const short* Wg0 = wbf + (size_t)NDEPTH * DD * DD;
  const short* Wl1 = wbf + (size_t)DD * DD;
  const short* Wg1 = wbf + (size_t)NDEPTH * DD * DD + (size_t)DD * DD;
  const int GEMMBLK = (NN + 127) / 128;   // 782

  // layer 0
  k_dualgemm<0><<<GEMMBLK, 512, 0, stream>>>(x, Wl0, Wg0, sb, tmpb, hg);
  k_agg<<<(NN + 3) / 4, 256, 0, stream>>>(rowptr, srow, snorm, (const unsigned int*)hg,
                                          (unsigned int*)tmpb);
  k_bnstats<<<NPB, 256, 0, stream>>>((const unsigned int*)tmpb, psum, pss);
  k_bnreduce<<<DD, 256, 0, stream>>>(psum, pss, gamma, beta, sb);

  // layer 1 (BN+ReLU folded into H load; in-place tmpb is row-safe)
  k_dualgemm<1><<<GEMMBLK, 512, 0, stream>>>(tmpb, Wl1, Wg1, sb, tmpb, hg);
  k_agg<<<(NN + 3) / 4, 256, 0, stream>>>(rowptr, srow, snorm, (const unsigned int*)hg,
                                          (unsigned int*)tmpb);
  k_bnstats<<<NPB, 256, 0, stream>>>((const unsigned int*)tmpb, psum, pss);
  k_bnreduce<<<DD, 256, 0, stream>>>(psum, pss, gamma + DD, beta + DD, sb);
  k_bnapply<<<(NN * DD / 4 + 255) / 256, 256, 0, stream>>>((const unsigned int*)tmpb, sb, out);
}

// Round 14
// 237.889 us; speedup vs baseline: 1.5549x; 1.0189x over previous
//
#include <hip/hip_runtime.h>
#include <hip/hip_bf16.h>

#define NN 100000
#define EE 500000
#define DD 128
#define NDEPTH 2
#define EPSV 1e-5f
#define NCHUNK 1024
#define NBLK ((NN + NCHUNK - 1) / NCHUNK)   // 98
#define NPB 2000     // bnstats blocks
#define RPB 50       // rows per bnstats block

typedef __attribute__((ext_vector_type(4))) float f32x4;
typedef __attribute__((ext_vector_type(4))) int i32x4;
typedef __attribute__((ext_vector_type(2))) unsigned int u32x2;
typedef __attribute__((ext_vector_type(8))) short bf16x8;
typedef __attribute__((ext_vector_type(4))) short bf16x4;

static __device__ __forceinline__ short f2bf(float x) {
  union { float f; unsigned u; } v; v.f = x;
  unsigned r = v.u + 0x7fffu + ((v.u >> 16) & 1u);  // round-to-nearest-even
  return (short)(r >> 16);
}
static __device__ __forceinline__ float bfbits2f(unsigned hi16) {
  union { unsigned u; float f; } v; v.u = hi16;
  return v.f;
}

// ---- convert both weight tensors to bf16 once ----
__global__ void k_convert_w(const float* __restrict__ lw, const float* __restrict__ gw,
                            short* __restrict__ wbf) {
  int i = blockIdx.x * 256 + threadIdx.x;
  if (i < NDEPTH * DD * DD) {
    wbf[i] = f2bf(lw[i]);
    wbf[NDEPTH * DD * DD + i] = f2bf(gw[i]);
  }
}

// ---- edge pass 1: ONE u64 atomic per edge: (count<<44) | fixed32(weight) ----
__global__ void k_edge1(const int* __restrict__ ei, const float* __restrict__ ew,
                        unsigned long long* __restrict__ dc) {
  int e = blockIdx.x * 256 + threadIdx.x;
  if (e < EE) {
    int c = ei[EE + e];
    unsigned long long pack = (1ULL << 44) |
        (unsigned long long)(ew[e] * 4294967296.0f + 0.5f);
    atomicAdd(dc + c, pack);
  }
}

// ---- unpack: dinv + int count (for the scan) ----
__global__ void k_dinv(const unsigned long long* __restrict__ dc,
                       float* __restrict__ dinv, int* __restrict__ cnt) {
  int i = blockIdx.x * 256 + threadIdx.x;
  if (i < NN) {
    unsigned long long v = dc[i];
    cnt[i] = (int)(v >> 44);
    float deg = (float)(v & ((1ULL << 44) - 1)) * (1.0f / 4294967296.0f);
    dinv[i] = deg > 0.f ? rsqrtf(deg) : 0.f;
  }
}

// ---- scan stage 1 ----
__global__ __launch_bounds__(256) void k_scan_part(const int* __restrict__ cnt,
                                                   int* __restrict__ part) {
  int b = blockIdx.x, t = threadIdx.x, lane = t & 63, wid = t >> 6;
  int base = b * NCHUNK + t * 4;
  int s = 0;
  if (base + 3 < NN) {
    i32x4 v = *(const i32x4*)(cnt + base);
    s = v[0] + v[1] + v[2] + v[3];
  } else {
    for (int j = 0; j < 4; ++j) if (base + j < NN) s += cnt[base + j];
  }
  for (int d = 32; d > 0; d >>= 1) s += __shfl_down(s, d);
  __shared__ int wsum[4];
  if (lane == 0) wsum[wid] = s;
  __syncthreads();
  if (t == 0) part[b] = wsum[0] + wsum[1] + wsum[2] + wsum[3];
}

// ---- scan stage 2 ----
__global__ void k_scan_mid(int* __restrict__ part, int* __restrict__ rowptr) {
  __shared__ int sm[128];
  int t = threadIdx.x;
  int v = (t < NBLK) ? part[t] : 0;
  sm[t] = v;
  __syncthreads();
  for (int off = 1; off < 128; off <<= 1) {
    int a = sm[t];
    int b = (t >= off) ? sm[t - off] : 0;
    __syncthreads();
    sm[t] = a + b;
    __syncthreads();
  }
  if (t < NBLK) part[t] = (t == 0) ? 0 : sm[t - 1];
  if (t == 127) rowptr[NN] = sm[127];
}

// ---- scan stage 3 ----
__global__ __launch_bounds__(256) void k_scan_final(const int* __restrict__ cnt,
    const int* __restrict__ part, int* __restrict__ rowptr, int* __restrict__ cursor) {
  int b = blockIdx.x, t = threadIdx.x, lane = t & 63, wid = t >> 6;
  int base = b * NCHUNK + t * 4;
  int c0 = 0, c1 = 0, c2 = 0, c3 = 0;
  if (base + 3 < NN) {
    i32x4 v = *(const i32x4*)(cnt + base);
    c0 = v[0]; c1 = v[1]; c2 = v[2]; c3 = v[3];
  } else {
    if (base < NN) c0 = cnt[base];
    if (base + 1 < NN) c1 = cnt[base + 1];
    if (base + 2 < NN) c2 = cnt[base + 2];
    if (base + 3 < NN) c3 = cnt[base + 3];
  }
  int s = c0 + c1 + c2 + c3;
  int v = s;
  for (int d = 1; d < 64; d <<= 1) {
    int u = __shfl_up(v, d);
    if (lane >= d) v += u;
  }
  __shared__ int wsum[4];
  if (lane == 63) wsum[wid] = v;
  __syncthreads();
  int woff = 0;
  for (int w = 0; w < wid; ++w) woff += wsum[w];
  int excl = part[b] + woff + (v - s);
  if (base < NN)     { rowptr[base]     = excl; cursor[base]     = excl; excl += c0; }
  if (base + 1 < NN) { rowptr[base + 1] = excl; cursor[base + 1] = excl; excl += c1; }
  if (base + 2 < NN) { rowptr[base + 2] = excl; cursor[base + 2] = excl; excl += c2; }
  if (base + 3 < NN) { rowptr[base + 3] = excl; cursor[base + 3] = excl; }
}

// ---- edge pass 2: bucket ONE 8B record {row, ew} by col (no dinv needed) ----
__global__ void k_edge2(const int* __restrict__ ei, const float* __restrict__ ew,
                        int* __restrict__ cursor, int2* __restrict__ eb) {
  int e = blockIdx.x * 256 + threadIdx.x;
  if (e < EE) {
    int r = ei[e], c = ei[EE + e];
    int pos = atomicAdd(cursor + c, 1);
    int2 rec;
    rec.x = r;
    rec.y = __float_as_int(ew[e]);
    eb[pos] = rec;
  }
}

// ---- dual GEMM, LDS-staged weights. 512 threads = 8 waves x 16 rows.
// hl -> tmpb (bf16), hg' = dinv[row] * (H@Wg^T) -> hg (bf16).
// APPLY=1: input is bf16 pre-BN h, apply per-column scale/bias + ReLU before use.
template<int APPLY>
__global__ __launch_bounds__(512) void k_dualgemm(const void* __restrict__ Hv,
    const short* __restrict__ Wl, const short* __restrict__ Wg,
    const float* __restrict__ sb, const float* __restrict__ dinvp,
    unsigned short* __restrict__ tmpo, unsigned short* __restrict__ hg) {
  __shared__ short lw[2 * DD * DD];   // 64 KB
  int tid = threadIdx.x;

  // stage: 4096 16B-units; swizzled global source -> linear LDS
#pragma unroll
  for (int c = 0; c < 8; ++c) {
    int q = c * 512 + tid;
    int region = q >> 11;            // 0 = Wl, 1 = Wg
    int row = (q >> 4) & 127;
    int u = q & 15;
    const short* src = (region ? Wg : Wl) + row * DD + ((u ^ (row & 7)) * 8);
    *(bf16x8*)(lw + q * 8) = *(const bf16x8*)src;
  }

  int lane = tid & 63, wv = tid >> 6;
  int row0 = blockIdx.x * 128 + wv * 16;
  int m = lane & 15, g = lane >> 4;

  bf16x8 hb[4];
  float dv = 0.f;
  if (row0 < NN) {
    dv = dinvp[row0 + m];
#pragma unroll
    for (int s = 0; s < 4; ++s) {
      float f[8];
      if (APPLY) {
        const unsigned short* H = (const unsigned short*)Hv;
        bf16x8 hv = *(const bf16x8*)(H + (size_t)(row0 + m) * DD + s * 32 + g * 8);
#pragma unroll
        for (int k2 = 0; k2 < 8; ++k2)
          f[k2] = bfbits2f(((unsigned)(unsigned short)hv[k2]) << 16);
      } else {
        const float* H = (const float*)Hv;
        f32x4 v0 = *(const f32x4*)(H + (size_t)(row0 + m) * DD + s * 32 + g * 8);
        f32x4 v1 = *(const f32x4*)(H + (size_t)(row0 + m) * DD + s * 32 + g * 8 + 4);
#pragma unroll
        for (int k2 = 0; k2 < 4; ++k2) { f[k2] = v0[k2]; f[k2 + 4] = v1[k2]; }
      }
      if (APPLY) {
        f32x4 sc0 = *(const f32x4*)(sb + s * 32 + g * 8);
        f32x4 sc1 = *(const f32x4*)(sb + s * 32 + g * 8 + 4);
        f32x4 bi0 = *(const f32x4*)(sb + DD + s * 32 + g * 8);
        f32x4 bi1 = *(const f32x4*)(sb + DD + s * 32 + g * 8 + 4);
#pragma unroll
        for (int k2 = 0; k2 < 4; ++k2) {
          f[k2]     = fmaxf(f[k2]     * sc0[k2] + bi0[k2], 0.f);
          f[k2 + 4] = fmaxf(f[k2 + 4] * sc1[k2] + bi1[k2], 0.f);
        }
      }
      bf16x8 tt;
#pragma unroll
      for (int k2 = 0; k2 < 8; ++k2) tt[k2] = f2bf(f[k2]);
      hb[s] = tt;
    }
  }

  __syncthreads();
  if (row0 >= NN) return;

  int mx = m & 7;
#pragma unroll
  for (int t = 0; t < 8; ++t) {
    f32x4 accl; accl[0] = 0.f; accl[1] = 0.f; accl[2] = 0.f; accl[3] = 0.f;
    f32x4 accg = accl;
#pragma unroll
    for (int s = 0; s < 4; ++s) {
      int u = (s * 4 + g) ^ mx;
      int base = (t * 16 + m) * DD + u * 8;
      bf16x8 wlf = *(const bf16x8*)(lw + base);
      bf16x8 wgf = *(const bf16x8*)(lw + DD * DD + base);
      accl = __builtin_amdgcn_mfma_f32_16x16x32_bf16(wlf, hb[s], accl, 0, 0, 0);
      accg = __builtin_amdgcn_mfma_f32_16x16x32_bf16(wgf, hb[s], accg, 0, 0, 0);
    }
    size_t r = (size_t)(row0 + m);
    bf16x4 l4, h4;
    l4[0] = f2bf(accl[0]); l4[1] = f2bf(accl[1]); l4[2] = f2bf(accl[2]); l4[3] = f2bf(accl[3]);
    h4[0] = f2bf(accg[0] * dv); h4[1] = f2bf(accg[1] * dv);
    h4[2] = f2bf(accg[2] * dv); h4[3] = f2bf(accg[3] * dv);
    *(bf16x4*)(tmpo + r * DD + t * 16 + g * 4) = l4;
    *(bf16x4*)(hg + r * DD + t * 16 + g * 4) = h4;
  }
}

// ---- aggregation: one wave per node, 4-way edge unroll (4 concurrent gather chains).
// tmpb[node] (bf16) += dinv[node] * sum ew * hg'[srcrow]  (hg' pre-scaled by dinv[row]).
__global__ __launch_bounds__(256) void k_agg(const int* __restrict__ rowptr,
    const int2* __restrict__ eb, const float* __restrict__ dinv,
    const unsigned int* __restrict__ hgu, unsigned int* __restrict__ tmpu) {
  int node = (blockIdx.x * 256 + (int)threadIdx.x) >> 6;
  int lane = threadIdx.x & 63;
  if (node >= NN) return;
  node = __builtin_amdgcn_readfirstlane(node);
  int beg = rowptr[node], end = rowptr[node + 1];
  float ax = 0.f, ay = 0.f;
  int j = beg;
  for (; j + 3 < end; j += 4) {
    int2 e0 = eb[j], e1 = eb[j + 1], e2 = eb[j + 2], e3 = eb[j + 3];
    unsigned u0 = hgu[e0.x * 64 + lane];
    unsigned u1 = hgu[e1.x * 64 + lane];
    unsigned u2 = hgu[e2.x * 64 + lane];
    unsigned u3 = hgu[e3.x * 64 + lane];
    float w0 = __int_as_float(e0.y), w1 = __int_as_float(e1.y);
    float w2 = __int_as_float(e2.y), w3 = __int_as_float(e3.y);
    ax += w0 * bfbits2f(u0 << 16) + w1 * bfbits2f(u1 << 16)
        + w2 * bfbits2f(u2 << 16) + w3 * bfbits2f(u3 << 16);
    ay += w0 * bfbits2f(u0 & 0xffff0000u) + w1 * bfbits2f(u1 & 0xffff0000u)
        + w2 * bfbits2f(u2 & 0xffff0000u) + w3 * bfbits2f(u3 & 0xffff0000u);
  }
  for (; j < end; ++j) {
    int2 e0 = eb[j];
    float w = __int_as_float(e0.y);
    unsigned u = hgu[e0.x * 64 + lane];
    ax += w * bfbits2f(u << 16);
    ay += w * bfbits2f(u & 0xffff0000u);
  }
  float dvn = dinv[node];
  ax *= dvn; ay *= dvn;
  unsigned* tp = tmpu + (size_t)node * 64 + lane;
  unsigned hl = *tp;
  float t0 = bfbits2f(hl << 16) + ax;
  float t1 = bfbits2f(hl & 0xffff0000u) + ay;
  unsigned p0 = (unsigned)(unsigned short)f2bf(t0);
  unsigned p1 = (unsigned)(unsigned short)f2bf(t1);
  *tp = p0 | (p1 << 16);
}

// ---- BN stats over bf16 h: 2000 blocks x 50 rows, coalesced u32x2, LDS reduce ----
__global__ __launch_bounds__(256) void k_bnstats(const unsigned int* __restrict__ h,
    float* __restrict__ psum, float* __restrict__ pss) {
  int b = blockIdx.x, t = threadIdx.x;
  int cg = t & 31, rs = t >> 5;          // column group (4 cols), row slice (0..7)
  f32x4 s; s[0] = 0.f; s[1] = 0.f; s[2] = 0.f; s[3] = 0.f;
  f32x4 q = s;
  int r0 = b * RPB;
  for (int r = r0 + rs; r < r0 + RPB; r += 8) {
    u32x2 u = *(const u32x2*)(h + (size_t)r * 64 + cg * 2);
    f32x4 v;
    v[0] = bfbits2f(u[0] << 16); v[1] = bfbits2f(u[0] & 0xffff0000u);
    v[2] = bfbits2f(u[1] << 16); v[3] = bfbits2f(u[1] & 0xffff0000u);
    s += v; q += v * v;
  }
  __shared__ f32x4 ls[8][32], lq[8][32];
  ls[rs][cg] = s; lq[rs][cg] = q;
  __syncthreads();
  if (t < 32) {
    f32x4 a = ls[0][t], qq = lq[0][t];
#pragma unroll
    for (int k = 1; k < 8; ++k) { a += ls[k][t]; qq += lq[k][t]; }
#pragma unroll
    for (int c = 0; c < 4; ++c) {
      psum[(t * 4 + c) * NPB + b] = a[c];
      pss [(t * 4 + c) * NPB + b] = qq[c];
    }
  }
}

// ---- reduce partials -> per-column scale/bias (folds gamma/beta/rsqrt) ----
__global__ __launch_bounds__(256) void k_bnreduce(const float* __restrict__ psum,
    const float* __restrict__ pss, const float* __restrict__ gamma,
    const float* __restrict__ beta, float* __restrict__ sb) {
  int col = blockIdx.x, t = threadIdx.x;
  float s = 0.f, q = 0.f;
  for (int i = t; i < NPB; i += 256) { s += psum[col * NPB + i]; q += pss[col * NPB + i]; }
  for (int d = 32; d > 0; d >>= 1) { s += __shfl_down(s, d); q += __shfl_down(q, d); }
  __shared__ float lws[4], lwq[4];
  int wid = t >> 6, lane = t & 63;
  if (lane == 0) { lws[wid] = s; lwq[wid] = q; }
  __syncthreads();
  if (t == 0) {
    float S = lws[0] + lws[1] + lws[2] + lws[3];
    float Q = lwq[0] + lwq[1] + lwq[2] + lwq[3];
    float mean = S * (1.f / NN);
    float var = Q * (1.f / NN) - mean * mean;
    float sc = rsqrtf(var + EPSV) * gamma[col];
    sb[col] = sc;
    sb[DD + col] = beta[col] - mean * sc;
  }
}

// ---- final BN apply: bf16 h -> f32 out, x*scale + bias (no relu) ----
__global__ void k_bnapply(const unsigned int* __restrict__ hb, const float* __restrict__ sb,
                          float* __restrict__ out) {
  int i = blockIdx.x * 256 + threadIdx.x;   // over NN*DD/4
  if (i >= NN * DD / 4) return;
  int d0 = (i * 4) & (DD - 1);
  u32x2 u = *(const u32x2*)(hb + i * 2);
  f32x4 o;
  o[0] = bfbits2f(u[0] << 16)          * sb[d0]     + sb[DD + d0];
  o[1] = bfbits2f(u[0] & 0xffff0000u)  * sb[d0 + 1] + sb[DD + d0 + 1];
  o[2] = bfbits2f(u[1] << 16)          * sb[d0 + 2] + sb[DD + d0 + 2];
  o[3] = bfbits2f(u[1] & 0xffff0000u)  * sb[d0 + 3] + sb[DD + d0 + 3];
  ((f32x4*)out)[i] = o;
}

extern "C" void kernel_launch(void* const* d_in, const int* in_sizes, int n_in,
                              void* d_out, int out_size, void* d_ws, size_t ws_size,
                              hipStream_t stream) {
  const float* x     = (const float*)d_in[0];
  const int*   ei    = (const int*)d_in[1];
  const float* ew    = (const float*)d_in[2];
  const float* lin_w = (const float*)d_in[3];
  const float* gcn_w = (const float*)d_in[4];
  const float* gamma = (const float*)d_in[5];
  const float* beta  = (const float*)d_in[6];
  float* out = (float*)d_out;

  char* ws = (char*)d_ws;
  size_t off = 0;
  auto alloc = [&](size_t bytes) -> void* {
    void* p = ws + off;
    off += (bytes + 255) & ~(size_t)255;
    return p;
  };
  unsigned short* hg   = (unsigned short*)alloc((size_t)NN * DD * 2);  // bf16 (dinv-scaled)
  unsigned short* tmpb = (unsigned short*)alloc((size_t)NN * DD * 2);  // bf16 h
  int2*  eb     = (int2*)alloc((size_t)EE * 8);                         // {row, ew}
  unsigned long long* dc = (unsigned long long*)alloc((size_t)NN * 8);
  float* dinv   = (float*)alloc((size_t)NN * 4);
  int*   rowptr = (int*)alloc((size_t)(NN + 1) * 4);
  int*   cursor = (int*)alloc((size_t)NN * 4);
  int*   cnt    = (int*)alloc((size_t)NN * 4);
  int*   part   = (int*)alloc((size_t)NBLK * 4);
  short* wbf    = (short*)alloc((size_t)2 * NDEPTH * DD * DD * 2);
  float* psum   = (float*)alloc((size_t)DD * NPB * 4);
  float* pss    = (float*)alloc((size_t)DD * NPB * 4);
  float* sb     = (float*)alloc((size_t)2 * DD * 4);

  hipMemsetAsync(dc, 0, (size_t)NN * 8, stream);

  k_convert_w<<<(NDEPTH * DD * DD + 255) / 256, 256, 0, stream>>>(lin_w, gcn_w, wbf);
  k_edge1<<<(EE + 255) / 256, 256, 0, stream>>>(ei, ew, dc);
  k_dinv<<<(NN + 255) / 256, 256, 0, stream>>>(dc, dinv, cnt);
  k_scan_part<<<NBLK, 256, 0, stream>>>(cnt, part);
  k_scan_mid<<<1, 128, 0, stream>>>(part, rowptr);
  k_scan_final<<<NBLK, 256, 0, stream>>>(cnt, part, rowptr, cursor);
  k_edge2<<<(EE + 255) / 256, 256, 0, stream>>>(ei, ew, cursor, eb);

  const short* Wl0 = wbf;
  const short* Wg0 = wbf + (size_t)NDEPTH * DD * DD;
  const short* Wl1 = wbf + (size_t)DD * DD;
  const short* Wg1 = wbf + (size_t)NDEPTH * DD * DD + (size_t)DD * DD;
  const int GEMMBLK = (NN + 127) / 128;   // 782

  // layer 0
  k_dualgemm<0><<<GEMMBLK, 512, 0, stream>>>(x, Wl0, Wg0, sb, dinv, tmpb, hg);
  k_agg<<<(NN + 3) / 4, 256, 0, stream>>>(rowptr, eb, dinv, (const unsigned int*)hg,
                                          (unsigned int*)tmpb);
  k_bnstats<<<NPB, 256, 0, stream>>>((const unsigned int*)tmpb, psum, pss);
  k_bnreduce<<<DD, 256, 0, stream>>>(psum, pss, gamma, beta, sb);

  // layer 1 (BN+ReLU folded into H load; in-place tmpb is row-safe)
  k_dualgemm<1><<<GEMMBLK, 512, 0, stream>>>(tmpb, Wl1, Wg1, sb, dinv, tmpb, hg);
  k_agg<<<(NN + 3) / 4, 256, 0, stream>>>(rowptr, eb, dinv, (const unsigned int*)hg,
                                          (unsigned int*)tmpb);
  k_bnstats<<<NPB, 256, 0, stream>>>((const unsigned int*)tmpb, psum, pss);
  k_bnreduce<<<DD, 256, 0, stream>>>(psum, pss, gamma + DD, beta + DD, sb);
  k_bnapply<<<(NN * DD / 4 + 255) / 256, 256, 0, stream>>>((const unsigned int*)tmpb, sb, out);
}